// Round 7
// baseline (271.403 us; speedup 1.0000x reference)
//
#include <hip/hip_runtime.h>
#include <math.h>

// Spherical harmonics edge attributes, lmax=2.
// Outputs (concat flat): edge_vec [E,3] | edge_length [E] | edge_sh [E,9]
//
// Round-6 probe: MAXIMALLY SIMPLE structure. 1 edge/thread, no LDS, no
// barriers, pure load->compute->store with full-coverage strided accesses:
//  - edge_index: nt dword loads (single-use stream, stride-4, full coverage)
//  - shift:      plain scalar loads, compiler-merged to dwordx3 (stride-12
//                across lanes = contiguous 768B per wave instr, no waste)
//  - pos:        plain dwordx3 gathers (1.2MB, L2/L3-resident)
//  - out_vec:    merged dwordx3 nt store (stride-12, full line coverage per
//                wave instruction -> coalescer combines, nt safe)
//  - out_len:    nt dword store (stride-4, full coverage)
//  - out_sh:     merged x4/x4/x1 REGULAR stores (per-instruction coverage is
//                partial at stride-36; let L2 write-combine the lines)
// Zero LDS -> max occupancy; zero barriers -> latency hidden purely by TLP.
// Pure function of input buffers: deterministic by construction.

#define SQRT3 1.7320508075688772f
#define SQRT5 2.2360679774997896f

__global__ __launch_bounds__(256) void sh_edge_kernel(
    const float*  __restrict__ pos,       // [N,3]
    const int*    __restrict__ edge_index,// [2,E]
    const float*  __restrict__ shift,     // [E,3]
    float* __restrict__ out_vec,          // [E,3]
    float* __restrict__ out_len,          // [E]
    float* __restrict__ out_sh,           // [E,9]
    int n_edges)
{
    const int e = blockIdx.x * 256 + threadIdx.x;
    if (e >= n_edges) return;

    // streamed index loads (nt: single-use, keep L2 for pos)
    const int s = __builtin_nontemporal_load(&edge_index[e]);
    const int d = __builtin_nontemporal_load(&edge_index[n_edges + e]);

    // shift row: plain loads so the compiler merges to one dwordx3
    const float* sp = shift + 3 * (size_t)e;
    const float shx = sp[0], shy = sp[1], shz = sp[2];

    // pos gathers (L2-resident table)
    const float* ps = pos + 3 * (size_t)s;
    const float* pd = pos + 3 * (size_t)d;
    const float ax = ps[0], ay = ps[1], az = ps[2];
    const float bx = pd[0], by = pd[1], bz = pd[2];

    const float x = bx - ax - shx;
    const float y = by - ay - shy;
    const float z = bz - az - shz;

    // edge_vec: merged dwordx3 nt store (full coverage per wave instruction)
    {
        float* ov = out_vec + 3 * (size_t)e;
        __builtin_nontemporal_store(x, &ov[0]);
        __builtin_nontemporal_store(y, &ov[1]);
        __builtin_nontemporal_store(z, &ov[2]);
    }

    const float sq = x * x + y * y + z * z;
    const float r  = rsqrtf(sq);
    __builtin_nontemporal_store(sq * r, &out_len[e]);   // stride-4, full coverage

    const float nx = x * r, ny = y * r, nz = z * r;
    const float x2 = nx * nx, y2 = ny * ny, z2 = nz * nz;

    // edge_sh: regular stores (merged x4/x4/x1); L2 write-combines stride-36
    float* o = out_sh + 9 * (size_t)e;
    o[0] = 1.0f;
    o[1] = SQRT3 * nx;
    o[2] = SQRT3 * ny;
    o[3] = SQRT3 * nz;
    o[4] = SQRT5 * SQRT3 * nx * nz;
    o[5] = SQRT5 * SQRT3 * nx * ny;
    o[6] = SQRT5 * (y2 - 0.5f * (x2 + z2));
    o[7] = SQRT5 * SQRT3 * ny * nz;
    o[8] = SQRT5 * 0.5f * SQRT3 * (z2 - x2);
}

extern "C" void kernel_launch(void* const* d_in, const int* in_sizes, int n_in,
                              void* d_out, int out_size, void* d_ws, size_t ws_size,
                              hipStream_t stream) {
    const float* pos        = (const float*)d_in[0];
    const int*   edge_index = (const int*)d_in[1];
    const float* shift      = (const float*)d_in[2];

    const int n_edges = in_sizes[2] / 3;   // shift is [E,3]

    float* out_vec = (float*)d_out;                        // [E,3]
    float* out_len = (float*)d_out + 3 * (size_t)n_edges;  // [E]
    float* out_sh  = (float*)d_out + 4 * (size_t)n_edges;  // [E,9]

    const int blocks = (n_edges + 255) / 256;
    sh_edge_kernel<<<blocks, 256, 0, stream>>>(
        pos, edge_index, shift, out_vec, out_len, out_sh, n_edges);
}